// Round 4
// baseline (648.486 us; speedup 1.0000x reference)
//
#include <hip/hip_runtime.h>
#include <cstdint>
#include <cstddef>

// ============================================================================
// DualStateLinearAttention on MI355X — round 4
//  R3 post-mortem: GEMM throughput-bound per-CU; +4cyc/ds_read from bank
//  conflicts (frag rows at 64B stride -> 2/8 bank groups). Scans ~175us from
//  serial cumsums + conflicted per-block transposes.
//  This round:
//   (1) GEMM: BK=64 + gather-permuted global_load_lds (fetch chunk c^(row&7))
//       with matching XOR on frag reads -> conflict-free LDS, half the barriers.
//   (2) k_trg: one-time IN-PLACE per-(bh,chunk)-block transpose of Q,K,V and
//       gate-cumsum-transpose of G1,G2 (cumsum stored as fp16 in place).
//       Block region = 64 rows x 128 at stride HIDN; transposed element (d,t)
//       lives at (d>>1)*HIDN + (d&1)*64 + t. s1/s3 prologues become pure
//       vectorized loads; V-frags and S-frags come straight from global.
//   (3) s1/s3 rewritten on the transposed layouts; padded LDS (72/136) makes
//       every ds_read_b128/write conflict-free. Wo converted up-front.
// ============================================================================

#define BB     2
#define SEQ    2048
#define HIDN   2048
#define NH     16
#define DD     128
#define CHUNK  64
#define NCHUNK (SEQ / CHUNK)   // 32
#define NBH    (BB * NH)       // 32
#define NELC   8388608
#define WELC   4194304
static constexpr float QSCALE = 0.08838834764831845f;  // 128^-0.5

typedef __bf16 bf16_t;
typedef _Float16 half_t;
typedef short  short8 __attribute__((ext_vector_type(8)));
typedef float  f32x4  __attribute__((ext_vector_type(4)));
typedef float  float4v __attribute__((ext_vector_type(4)));

__device__ __forceinline__ float bf2f(short u) {
  return (float)__builtin_bit_cast(bf16_t, u);
}
__device__ __forceinline__ short f2bf(float f) {
  return __builtin_bit_cast(short, (bf16_t)f);
}
__device__ __forceinline__ float hf2f(short u) {
  return (float)__builtin_bit_cast(half_t, u);
}
__device__ __forceinline__ short f2hf(float f) {
  return __builtin_bit_cast(short, (half_t)f);
}

__device__ __forceinline__ void gload_lds16(const void* g, void* l) {
  __builtin_amdgcn_global_load_lds(
      (__attribute__((address_space(1))) unsigned int*)g,
      (__attribute__((address_space(3))) unsigned int*)l, 16, 0, 0);
}

// ---------------------------------------------------------------------------
// bf16 MFMA GEMM, BK=64, conflict-free swizzle. C[4096,2048] = A @ Bw^T.
// epi: 0 bf16, 1 gate (bias + logsigmoid/16 clamp), 2 fp32
// ---------------------------------------------------------------------------
__device__ __forceinline__ void gemm_body(const bf16_t* __restrict__ A,
                                          const bf16_t* __restrict__ Bw,
                                          const float*  __restrict__ bias,
                                          bf16_t* __restrict__ outb,
                                          float*  __restrict__ outf, int epi) {
  __shared__ bf16_t As[128 * 64];  // [row][8 chunks of 16B], chunk c holds
  __shared__ bf16_t Bs[128 * 64];  // global chunk c ^ (row&7)
  const int tm   = blockIdx.x * 128;
  const int tn   = blockIdx.y * 128;
  const int wave = threadIdx.x >> 6;
  const int lane = threadIdx.x & 63;
  const int wm   = (wave >> 1) * 64;
  const int wn   = (wave & 1) * 64;
  const int qd   = lane >> 4;
  const int l16  = lane & 15;
  const int ro   = l16 & 7;  // frag-row bank phase

  // staging: 1024 chunks/tile, 4 issues/wave/tile. lane: row-sub = lane>>3,
  // lds chunk-in-row c = lane&7, gathered global chunk gc = c ^ (lane>>3).
  const int gc   = (lane & 7) ^ (lane >> 3);
  const bf16_t* ga[4];
  const bf16_t* gb[4];
  bf16_t* la[4];
  bf16_t* lb[4];
#pragma unroll
  for (int u = 0; u < 4; u++) {
    const int row = wave * 32 + u * 8 + (lane >> 3);
    ga[u] = A  + (size_t)(tm + row) * HIDN + gc * 8;
    gb[u] = Bw + (size_t)(tn + row) * HIDN + gc * 8;
    la[u] = &As[(wave * 256 + u * 64) * 8];
    lb[u] = &Bs[(wave * 256 + u * 64) * 8];
  }

  f32x4 acc[4][4];
#pragma unroll
  for (int i = 0; i < 4; i++)
#pragma unroll
    for (int j = 0; j < 4; j++) acc[i][j] = (f32x4){0.f, 0.f, 0.f, 0.f};

  for (int k0 = 0; k0 < HIDN; k0 += 64) {
#pragma unroll
    for (int u = 0; u < 4; u++) { gload_lds16(ga[u], la[u]); ga[u] += 64; }
#pragma unroll
    for (int u = 0; u < 4; u++) { gload_lds16(gb[u], lb[u]); gb[u] += 64; }
    __syncthreads();
#pragma unroll
    for (int ks = 0; ks < 2; ks++) {
      const int g = ks * 4 + qd;
      short8 af[4], bfv[4];
#pragma unroll
      for (int t = 0; t < 4; t++)
        af[t] = *(const short8*)&As[(wm + t * 16 + l16) * 64 + (g ^ ro) * 8];
#pragma unroll
      for (int t = 0; t < 4; t++)
        bfv[t] = *(const short8*)&Bs[(wn + t * 16 + l16) * 64 + (g ^ ro) * 8];
#pragma unroll
      for (int i = 0; i < 4; i++)
#pragma unroll
        for (int j = 0; j < 4; j++)
          acc[i][j] = __builtin_amdgcn_mfma_f32_16x16x32_bf16(
              af[i], bfv[j], acc[i][j], 0, 0, 0);
    }
    __syncthreads();
  }

#pragma unroll
  for (int i = 0; i < 4; i++)
#pragma unroll
    for (int j = 0; j < 4; j++)
#pragma unroll
      for (int r = 0; r < 4; r++) {
        const int row = tm + wm + i * 16 + qd * 4 + r;
        const int col = tn + wn + j * 16 + l16;
        float v = acc[i][j][r];
        if (epi == 1) {
          v += bias[col];
          const float ls = fminf(v, 0.f) - log1pf(__expf(-fabsf(v)));
          v = fmaxf(ls * 0.0625f, -50.f);
        }
        if (epi == 2) outf[(size_t)row * HIDN + col] = v;
        else          outb[(size_t)row * HIDN + col] = (bf16_t)v;
      }
}

__global__ __launch_bounds__(256) void k_gemm_proj(
    const bf16_t* __restrict__ Xb,
    const bf16_t* __restrict__ W0, const bf16_t* __restrict__ W1,
    const bf16_t* __restrict__ W2, const bf16_t* __restrict__ W3,
    const bf16_t* __restrict__ W4,
    const float* __restrict__ bg1, const float* __restrict__ bg2,
    bf16_t* __restrict__ Qb, bf16_t* __restrict__ Kb, bf16_t* __restrict__ Vb,
    bf16_t* __restrict__ G1b, bf16_t* __restrict__ G2b) {
  const int z = blockIdx.z;
  const bf16_t* Ws[5] = {W0, W1, W2, W3, W4};
  bf16_t* Os[5] = {Qb, Kb, Vb, G1b, G2b};
  const float* bias = (z == 3) ? bg1 : ((z == 4) ? bg2 : nullptr);
  gemm_body(Xb, Ws[z], bias, Os[z], nullptr, (z >= 3) ? 1 : 0);
}

__global__ __launch_bounds__(256) void k_gemm_out(
    const bf16_t* __restrict__ attnB, const bf16_t* __restrict__ Wob,
    float* __restrict__ out) {
  gemm_body(attnB, Wob, nullptr, nullptr, out, 2);
}

// ---------------------------------------------------------------------------
// converts: y=0 X->Xb; y=1..4 Wq,Wk,Wv,Wg1 -> d_out slices; y=5 Wg2; y=6 Wo
// ---------------------------------------------------------------------------
__global__ __launch_bounds__(256) void k_cvt_all(
    const float* __restrict__ hid, const float* __restrict__ wq,
    const float* __restrict__ wk, const float* __restrict__ wv,
    const float* __restrict__ wg1, const float* __restrict__ wg2,
    const float* __restrict__ wo, bf16_t* __restrict__ Xb,
    bf16_t* __restrict__ Wd, bf16_t* __restrict__ Wcur,
    bf16_t* __restrict__ WoB) {
  const int y = blockIdx.y;
  const float* srcs[7] = {hid, wq, wk, wv, wg1, wg2, wo};
  bf16_t* dsts[7] = {Xb, Wd, Wd + WELC, Wd + 2 * WELC, Wd + 3 * WELC, Wcur,
                     WoB};
  const int n = (y == 0) ? NELC : WELC;
  const float* src = srcs[y];
  bf16_t* dst = dsts[y];
  const int idx = (blockIdx.x * 256 + threadIdx.x) * 4;
  if (idx < n) {
    const float4 f = *(const float4*)(src + idx);
    dst[idx + 0] = (bf16_t)f.x; dst[idx + 1] = (bf16_t)f.y;
    dst[idx + 2] = (bf16_t)f.z; dst[idx + 3] = (bf16_t)f.w;
  }
}

__global__ __launch_bounds__(256) void k_zero(float* __restrict__ out) {
  out[(size_t)blockIdx.x * 256 + threadIdx.x] = 0.f;
}

// ---------------------------------------------------------------------------
// k_trg: per-(bh,chunk)-block IN-PLACE transpose. z=0,1,2: Q,K,V raw bf16.
// z=3,4: G1,G2 -> inclusive cumsum over t (fp32 accum), stored fp16, + Btot.
// Transposed layout within region: (d,t) -> (d>>1)*HIDN + (d&1)*64 + t.
// ---------------------------------------------------------------------------
__global__ __launch_bounds__(256) void k_trg(
    bf16_t* __restrict__ Qb, bf16_t* __restrict__ Kb, bf16_t* __restrict__ Vb,
    bf16_t* __restrict__ G1b, bf16_t* __restrict__ G2b,
    float* __restrict__ Btot) {
  const int n = blockIdx.x, bh = blockIdx.y, z = blockIdx.z;
  const int b = bh >> 4, h = bh & 15;
  bf16_t* bufs[5] = {Qb, Kb, Vb, G1b, G2b};
  short* P = (short*)bufs[z];
  const size_t rbase = ((size_t)(b * SEQ + n * CHUNK)) * HIDN + h * DD;
  const int tid = threadIdx.x;
  __shared__ short L1[CHUNK * 136];  // [t][d] pad 136
  __shared__ short L2[DD * 72];      // [d][t] pad 72

#pragma unroll
  for (int k = 0; k < 4; k++) {
    const int v = tid + k * 256;  // 1024 vec8: t = v>>4, d0 = (v&15)*8
    const int t = v >> 4, d0 = (v & 15) * 8;
    const short8 x = *(const short8*)(P + rbase + (size_t)t * HIDN + d0);
#pragma unroll
    for (int j = 0; j < 8; j++) L1[t * 136 + d0 + j] = x[j];
  }
  __syncthreads();
  if (tid < DD) {
    const int d = tid;
    if (z >= 3) {
      float c = 0.f;
#pragma unroll
      for (int ch = 0; ch < 8; ch++) {
        short8 o;
#pragma unroll
        for (int j = 0; j < 8; j++) {
          c += bf2f(L1[(ch * 8 + j) * 136 + d]);
          o[j] = f2hf(c);
        }
        *(short8*)&L2[d * 72 + ch * 8] = o;
      }
      Btot[((size_t)((z - 3) * NBH + bh) * NCHUNK + n) * DD + d] = c;
    } else {
#pragma unroll
      for (int ch = 0; ch < 8; ch++) {
        short8 o;
#pragma unroll
        for (int j = 0; j < 8; j++) o[j] = L1[(ch * 8 + j) * 136 + d];
        *(short8*)&L2[d * 72 + ch * 8] = o;
      }
    }
  }
  __syncthreads();
#pragma unroll
  for (int k = 0; k < 4; k++) {
    const int v = tid + k * 256;  // out phys (r, x0..x0+7)
    const int r = v >> 4, x0 = (v & 15) * 8;
    const int d = 2 * r + (x0 >> 6), t0 = x0 & 63;
    const short8 o = *(const short8*)&L2[d * 72 + t0];
    *(short8*)(P + rbase + (size_t)r * HIDN + x0) = o;
  }
}

// ---------------------------------------------------------------------------
// S1: UT[dv][dk] = sum_s V[s][dv]*Khat[s][dk], Khat = k*exp(c63 - c).
// KT/GcT transposed layouts; V-frags from global; k2 LDS pad-72.
// ---------------------------------------------------------------------------
__global__ __launch_bounds__(256) void k_s1(
    const bf16_t* __restrict__ Kb, const bf16_t* __restrict__ Vb,
    const bf16_t* __restrict__ Gc, bf16_t* __restrict__ UT) {
  const int n = blockIdx.x, bh = blockIdx.y;
  const int b = bh >> 4, h = bh & 15;
  const size_t rbase = ((size_t)(b * SEQ + n * CHUNK)) * HIDN + h * DD;
  const int tid = threadIdx.x;
  __shared__ short k2L[DD * 72];  // [dk][s] pad 72

  if (tid < DD) {
    const int d = tid;
    const size_t row = rbase + (size_t)(d >> 1) * HIDN + (d & 1) * 64;
    const short* Kp = (const short*)Kb + row;
    const short* Gp = (const short*)Gc + row;
    const float c63 = hf2f(Gp[63]);
#pragma unroll
    for (int ch = 0; ch < 8; ch++) {
      const short8 kk = *(const short8*)(Kp + ch * 8);
      const short8 cc = *(const short8*)(Gp + ch * 8);
      short8 o;
#pragma unroll
      for (int j = 0; j < 8; j++)
        o[j] = f2bf(bf2f(kk[j]) * __expf(c63 - hf2f(cc[j])));
      *(short8*)&k2L[d * 72 + ch * 8] = o;
    }
  }
  __syncthreads();

  const int wave = tid >> 6, lane = tid & 63, qd = lane >> 4, l16 = lane & 15;
  const int m0 = (wave >> 1) * 64, n0 = (wave & 1) * 64;
  const short* Vp = (const short*)Vb;
  f32x4 acc[4][4];
#pragma unroll
  for (int i = 0; i < 4; i++)
#pragma unroll
    for (int j = 0; j < 4; j++) acc[i][j] = (f32x4){0.f, 0.f, 0.f, 0.f};
#pragma unroll
  for (int ks = 0; ks < 2; ks++) {
    const int ch = ks * 4 + qd;
    short8 af[4], bfv[4];
#pragma unroll
    for (int i = 0; i < 4; i++) {
      const int dv = m0 + i * 16 + l16;
      af[i] = *(const short8*)(Vp + rbase + (size_t)(dv >> 1) * HIDN +
                               (dv & 1) * 64 + ch * 8);
    }
#pragma unroll
    for (int j = 0; j < 4; j++)
      bfv[j] = *(const short8*)&k2L[(n0 + j * 16 + l16) * 72 + ch * 8];
#pragma unroll
    for (int i = 0; i < 4; i++)
#pragma unroll
      for (int j = 0; j < 4; j++)
        acc[i][j] = __builtin_amdgcn_mfma_f32_16x16x32_bf16(af[i], bfv[j],
                                                            acc[i][j], 0, 0, 0);
  }
  bf16_t* Uo = UT + ((size_t)bh * NCHUNK + n) * (size_t)(DD * DD);
#pragma unroll
  for (int i = 0; i < 4; i++)
#pragma unroll
    for (int j = 0; j < 4; j++)
#pragma unroll
      for (int r = 0; r < 4; r++)
        Uo[(size_t)(m0 + i * 16 + qd * 4 + r) * DD + n0 + j * 16 + l16] =
            (bf16_t)acc[i][j][r];
}

// ---------------------------------------------------------------------------
// S2: sequential chunk combine (S^T states in place over U^T).
// ---------------------------------------------------------------------------
__global__ __launch_bounds__(256) void k_s2(bf16_t* __restrict__ UT,
                                            const float* __restrict__ Btot) {
  const int dg = blockIdx.x, bh = blockIdx.y;
  const int dv = dg * 8 + (threadIdx.x >> 5);
  const int dk0 = (threadIdx.x & 31) * 4;
  float st[4] = {0.f, 0.f, 0.f, 0.f};
  for (int nn = 0; nn < NCHUNK; nn++) {
    short* p =
        (short*)UT + ((size_t)bh * NCHUNK + nn) * (size_t)(DD * DD) + dv * DD + dk0;
    const float4v bp =
        *(const float4v*)(Btot + ((size_t)bh * NCHUNK + nn) * DD + dk0);
    short u0 = p[0], u1 = p[1], u2 = p[2], u3 = p[3];
    p[0] = f2bf(st[0]); p[1] = f2bf(st[1]);
    p[2] = f2bf(st[2]); p[3] = f2bf(st[3]);
    st[0] = st[0] * __expf(bp[0]) + bf2f(u0);
    st[1] = st[1] * __expf(bp[1]) + bf2f(u1);
    st[2] = st[2] * __expf(bp[2]) + bf2f(u2);
    st[3] = st[3] * __expf(bp[3]) + bf2f(u3);
  }
}

// ---------------------------------------------------------------------------
// S3 (fused intra+inter): P = (qh2 . k2) causal-masked; O = P@V + qh2@S.
// qh2 = q*w*scale*exp(c), k2 = k*exp(-c). QT/KT/GcT transposed layouts;
// V-frags and S-frags from global. attn (+)= O.
// ---------------------------------------------------------------------------
template <int ACC>
__global__ __launch_bounds__(256) void k_s3(
    const bf16_t* __restrict__ Qb, const bf16_t* __restrict__ Kb,
    const bf16_t* __restrict__ Vb, const bf16_t* __restrict__ Gc,
    const bf16_t* __restrict__ UT, const float* __restrict__ alpha,
    bf16_t* __restrict__ attn) {
  const int n = blockIdx.x, bh = blockIdx.y;
  const int b = bh >> 4, h = bh & 15;
  const size_t rbase = ((size_t)(b * SEQ + n * CHUNK)) * HIDN + h * DD;
  const int tid = threadIdx.x;
  __shared__ short qhL[CHUNK * 136];  // [t][d] pad 136
  __shared__ short k2L[CHUNK * 136];  // [s][d] pad 136
  __shared__ short PsL[CHUNK * 72];   // [t][s] pad 72
  const float mx = fmaxf(alpha[0], alpha[1]);
  const float x0 = __expf(alpha[0] - mx), x1 = __expf(alpha[1] - mx);
  const float w = (ACC ? x1 : x0) / (x0 + x1);

  if (tid < DD) {
    const int d = tid;
    const size_t row = rbase + (size_t)(d >> 1) * HIDN + (d & 1) * 64;
    const short* Qp = (const short*)Qb + row;
    const short* Kp = (const short*)Kb + row;
    const short* Gp = (const short*)Gc + row;
    const float wsc = w * QSCALE;
#pragma unroll
    for (int ch = 0; ch < 8; ch++) {
      const short8 qq = *(const short8*)(Qp + ch * 8);
      const short8 kk = *(const short8*)(Kp + ch * 8);
      const short8 cc = *(const short8*)(Gp + ch * 8);
#pragma unroll
      for (int j = 0; j < 8; j++) {
        const float c = hf2f(cc[j]);
        const int t = ch * 8 + j;
        qhL[t * 136 + d] = f2bf(bf2f(qq[j]) * wsc * __expf(c));
        k2L[t * 136 + d] = f2bf(bf2f(kk[j]) * __expf(-c));
      }
    }
  }
  __syncthreads();

  const int wave = tid >> 6, lane = tid & 63, qd = lane >> 4, l16 = lane & 15;
  {  // P: wave owns t-rows [wave*16, +16)
    f32x4 pacc[4];
#pragma unroll
    for (int j = 0; j < 4; j++) pacc[j] = (f32x4){0.f, 0.f, 0.f, 0.f};
#pragma unroll
    for (int ks = 0; ks < 4; ks++) {
      const int ch = ks * 4 + qd;
      const short8 a = *(const short8*)&qhL[(wave * 16 + l16) * 136 + ch * 8];
#pragma unroll
      for (int j = 0; j < 4; j++) {
        const short8 bq = *(const short8*)&k2L[(j * 16 + l16) * 136 + ch * 8];
        pacc[j] = __builtin_amdgcn_mfma_f32_16x16x32_bf16(a, bq, pacc[j], 0, 0, 0);
      }
    }
#pragma unroll
    for (int j = 0; j < 4; j++)
#pragma unroll
      for (int r = 0; r < 4; r++) {
        const int t = wave * 16 + qd * 4 + r, s = j * 16 + l16;
        PsL[t * 72 + s] = (t >= s) ? f2bf(pacc[j][r]) : (short)0;
      }
  }
  __syncthreads();

  // O = Ps@V + qh2@S : wave owns dv cols [wave*32, +32)
  const short* Sp =
      (const short*)UT + ((size_t)bh * NCHUNK + n) * (size_t)(DD * DD);
  const short* Vp = (const short*)Vb;
  const int nw = wave * 32;
  f32x4 acc[4][2];
#pragma unroll
  for (int i = 0; i < 4; i++)
#pragma unroll
    for (int j = 0; j < 2; j++) acc[i][j] = (f32x4){0.f, 0.f, 0.f, 0.f};
#pragma unroll
  for (int ks = 0; ks < 2; ks++) {  // intra, K = s
    const int ch = ks * 4 + qd;
    short8 a[4];
#pragma unroll
    for (int i = 0; i < 4; i++)
      a[i] = *(const short8*)&PsL[(i * 16 + l16) * 72 + ch * 8];
#pragma unroll
    for (int j = 0; j < 2; j++) {
      const int dv = nw + j * 16 + l16;
      const short8 bq = *(const short8*)(Vp + rbase + (size_t)(dv >> 1) * HIDN +
                                         (dv & 1) * 64 + ch * 8);
#pragma unroll
      for (int i = 0; i < 4; i++)
        acc[i][j] = __builtin_amdgcn_mfma_f32_16x16x32_bf16(a[i], bq,
                                                            acc[i][j], 0, 0, 0);
    }
  }
#pragma unroll
  for (int ks = 0; ks < 4; ks++) {  // inter, K = dk, S^T rows from global
    const int ch = ks * 4 + qd;
    short8 a[4];
#pragma unroll
    for (int i = 0; i < 4; i++)
      a[i] = *(const short8*)&qhL[(i * 16 + l16) * 136 + ch * 8];
#pragma unroll
    for (int j = 0; j < 2; j++) {
      const short8 bq =
          *(const short8*)(Sp + (size_t)(nw + j * 16 + l16) * DD + ch * 8);
#pragma unroll
      for (int i = 0; i < 4; i++)
        acc[i][j] = __builtin_amdgcn_mfma_f32_16x16x32_bf16(a[i], bq,
                                                            acc[i][j], 0, 0, 0);
    }
  }
#pragma unroll
  for (int i = 0; i < 4; i++)
#pragma unroll
    for (int j = 0; j < 2; j++)
#pragma unroll
      for (int r = 0; r < 4; r++) {
        const int t = i * 16 + qd * 4 + r;
        const int dv = nw + j * 16 + l16;
        bf16_t* p = &attn[rbase + (size_t)t * HIDN + dv];
        if (ACC) *p = (bf16_t)((float)*p + acc[i][j][r]);
        else     *p = (bf16_t)acc[i][j][r];
      }
}

// ---------------------------------------------------------------------------
extern "C" void kernel_launch(void* const* d_in, const int* in_sizes, int n_in,
                              void* d_out, int out_size, void* d_ws,
                              size_t ws_size, hipStream_t stream) {
  const float* hid  = (const float*)d_in[0];
  const float* wq   = (const float*)d_in[1];
  const float* wk   = (const float*)d_in[2];
  const float* wv   = (const float*)d_in[3];
  const float* wo   = (const float*)d_in[4];
  const float* wg1  = (const float*)d_in[5];
  const float* bg1  = (const float*)d_in[6];
  const float* wg2  = (const float*)d_in[7];
  const float* bg2  = (const float*)d_in[8];
  const float* alph = (const float*)d_in[9];
  float* out = (float*)d_out;
  (void)in_sizes; (void)n_in; (void)out_size;

  char* ws = (char*)d_ws;
  size_t off = 0;
  auto alloc = [&](size_t bytes) -> void* {
    void* p = ws + off;
    off += (bytes + 255) & ~(size_t)255;
    return p;
  };
  const size_t NEL = NELC, WEL = WELC;
  bf16_t* Xb   = (bf16_t*)alloc(NEL * 2);  // X; reused as attn
  bf16_t* Wcur = (bf16_t*)alloc(WEL * 2);  // Wg2
  bf16_t* WoB  = (bf16_t*)alloc(WEL * 2);  // Wo
  bf16_t* Qb   = (bf16_t*)alloc(NEL * 2);
  bf16_t* Kb   = (bf16_t*)alloc(NEL * 2);
  bf16_t* Vb   = (bf16_t*)alloc(NEL * 2);
  bf16_t* G1b  = (bf16_t*)alloc(NEL * 2);
  bf16_t* G2b  = (bf16_t*)alloc(NEL * 2);
  float*  Btot = (float*) alloc((size_t)2 * NBH * NCHUNK * DD * 4);
  bf16_t* Wd = (bf16_t*)d_out;  // 4 bf16 weights, then U/S states, then out
  bf16_t* UT = (bf16_t*)d_out;

  if (off > ws_size) {  // diagnostic fallback
    k_zero<<<dim3((unsigned)(NEL / 256)), 256, 0, stream>>>(out);
    return;
  }

  k_cvt_all<<<dim3(8192, 7), 256, 0, stream>>>(hid, wq, wk, wv, wg1, wg2, wo,
                                               Xb, Wd, Wcur, WoB);
  k_gemm_proj<<<dim3(32, 16, 5), 256, 0, stream>>>(
      Xb, Wd, Wd + WEL, Wd + 2 * WEL, Wd + 3 * WEL, Wcur, bg1, bg2, Qb, Kb, Vb,
      G1b, G2b);
  k_trg<<<dim3(NCHUNK, NBH, 5), 256, 0, stream>>>(Qb, Kb, Vb, G1b, G2b, Btot);

  const dim3 gs(NCHUNK, NBH), g2(16, NBH);
  const size_t BSTRIDE = (size_t)NBH * NCHUNK * DD;
  // e = 0
  k_s1<<<gs, 256, 0, stream>>>(Kb, Vb, G1b, UT);
  k_s2<<<g2, 256, 0, stream>>>(UT, Btot);
  k_s3<0><<<gs, 256, 0, stream>>>(Qb, Kb, Vb, G1b, UT, alph, Xb);
  // e = 1
  k_s1<<<gs, 256, 0, stream>>>(Kb, Vb, G2b, UT);
  k_s2<<<g2, 256, 0, stream>>>(UT, Btot + BSTRIDE);
  k_s3<1><<<gs, 256, 0, stream>>>(Qb, Kb, Vb, G2b, UT, alph, Xb);

  k_gemm_out<<<dim3(32, 16), 256, 0, stream>>>(Xb, WoB, out);
}

// Round 5
// 591.062 us; speedup vs baseline: 1.0972x; 1.0972x over previous
//
#include <hip/hip_runtime.h>
#include <cstdint>
#include <cstddef>

// ============================================================================
// DualStateLinearAttention on MI355X — round 5
//  R4 lesson: scattered global frag reads lose to coalesced-stage + LDS frags.
//  This round: natural layouts; k_gc precomputes gate cumsum (fp16 in place);
//  k_sA fuses U-build + intra-chunk output per e (one read of Q,K,V,G);
//  k_s3b does inter-chunk with gload16-staged S + qh rebuild. GEMM = R4 core
//  (BK=64, gather-swizzled staging, conflict-free — proven).
// Pipeline: cvt -> proj(5x fused) -> gc -> [sA -> s2 -> s3b] x2 -> out-GEMM.
// ============================================================================

#define BB     2
#define SEQ    2048
#define HIDN   2048
#define NH     16
#define DD     128
#define CHUNK  64
#define NCHUNK (SEQ / CHUNK)   // 32
#define NBH    (BB * NH)       // 32
#define NELC   8388608
#define WELC   4194304
static constexpr float QSCALE = 0.08838834764831845f;  // 128^-0.5

typedef __bf16 bf16_t;
typedef _Float16 half_t;
typedef short  short8 __attribute__((ext_vector_type(8)));
typedef float  f32x4  __attribute__((ext_vector_type(4)));

__device__ __forceinline__ float bf2f(short u) {
  return (float)__builtin_bit_cast(bf16_t, u);
}
__device__ __forceinline__ short f2bf(float f) {
  return __builtin_bit_cast(short, (bf16_t)f);
}
__device__ __forceinline__ float hf2f(short u) {
  return (float)__builtin_bit_cast(half_t, u);
}
__device__ __forceinline__ short f2hf(float f) {
  return __builtin_bit_cast(short, (half_t)f);
}

__device__ __forceinline__ void gload_lds16(const void* g, void* l) {
  __builtin_amdgcn_global_load_lds(
      (__attribute__((address_space(1))) unsigned int*)g,
      (__attribute__((address_space(3))) unsigned int*)l, 16, 0, 0);
}

// ---------------------------------------------------------------------------
// bf16 MFMA GEMM, BK=64, gather-swizzled staging (R4, proven conflict-free).
// ---------------------------------------------------------------------------
__device__ __forceinline__ void gemm_body(const bf16_t* __restrict__ A,
                                          const bf16_t* __restrict__ Bw,
                                          const float*  __restrict__ bias,
                                          bf16_t* __restrict__ outb,
                                          float*  __restrict__ outf, int epi) {
  __shared__ bf16_t As[128 * 64];
  __shared__ bf16_t Bs[128 * 64];
  const int tm   = blockIdx.x * 128;
  const int tn   = blockIdx.y * 128;
  const int wave = threadIdx.x >> 6;
  const int lane = threadIdx.x & 63;
  const int wm   = (wave >> 1) * 64;
  const int wn   = (wave & 1) * 64;
  const int qd   = lane >> 4;
  const int l16  = lane & 15;
  const int ro   = l16 & 7;

  const int gc = (lane & 7) ^ (lane >> 3);
  const bf16_t* ga[4];
  const bf16_t* gb[4];
  bf16_t* la[4];
  bf16_t* lb[4];
#pragma unroll
  for (int u = 0; u < 4; u++) {
    const int row = wave * 32 + u * 8 + (lane >> 3);
    ga[u] = A  + (size_t)(tm + row) * HIDN + gc * 8;
    gb[u] = Bw + (size_t)(tn + row) * HIDN + gc * 8;
    la[u] = &As[(wave * 256 + u * 64) * 8];
    lb[u] = &Bs[(wave * 256 + u * 64) * 8];
  }

  f32x4 acc[4][4];
#pragma unroll
  for (int i = 0; i < 4; i++)
#pragma unroll
    for (int j = 0; j < 4; j++) acc[i][j] = (f32x4){0.f, 0.f, 0.f, 0.f};

  for (int k0 = 0; k0 < HIDN; k0 += 64) {
#pragma unroll
    for (int u = 0; u < 4; u++) { gload_lds16(ga[u], la[u]); ga[u] += 64; }
#pragma unroll
    for (int u = 0; u < 4; u++) { gload_lds16(gb[u], lb[u]); gb[u] += 64; }
    __syncthreads();
#pragma unroll
    for (int ks = 0; ks < 2; ks++) {
      const int g = ks * 4 + qd;
      short8 af[4], bfv[4];
#pragma unroll
      for (int t = 0; t < 4; t++)
        af[t] = *(const short8*)&As[(wm + t * 16 + l16) * 64 + (g ^ ro) * 8];
#pragma unroll
      for (int t = 0; t < 4; t++)
        bfv[t] = *(const short8*)&Bs[(wn + t * 16 + l16) * 64 + (g ^ ro) * 8];
#pragma unroll
      for (int i = 0; i < 4; i++)
#pragma unroll
        for (int j = 0; j < 4; j++)
          acc[i][j] = __builtin_amdgcn_mfma_f32_16x16x32_bf16(
              af[i], bfv[j], acc[i][j], 0, 0, 0);
    }
    __syncthreads();
  }

#pragma unroll
  for (int i = 0; i < 4; i++)
#pragma unroll
    for (int j = 0; j < 4; j++)
#pragma unroll
      for (int r = 0; r < 4; r++) {
        const int row = tm + wm + i * 16 + qd * 4 + r;
        const int col = tn + wn + j * 16 + l16;
        float v = acc[i][j][r];
        if (epi == 1) {
          v += bias[col];
          const float ls = fminf(v, 0.f) - log1pf(__expf(-fabsf(v)));
          v = fmaxf(ls * 0.0625f, -50.f);
        }
        if (epi == 2) outf[(size_t)row * HIDN + col] = v;
        else          outb[(size_t)row * HIDN + col] = (bf16_t)v;
      }
}

__global__ __launch_bounds__(256) void k_gemm_proj(
    const bf16_t* __restrict__ Xb,
    const bf16_t* __restrict__ W0, const bf16_t* __restrict__ W1,
    const bf16_t* __restrict__ W2, const bf16_t* __restrict__ W3,
    const bf16_t* __restrict__ W4,
    const float* __restrict__ bg1, const float* __restrict__ bg2,
    bf16_t* __restrict__ Qb, bf16_t* __restrict__ Kb, bf16_t* __restrict__ Vb,
    bf16_t* __restrict__ G1b, bf16_t* __restrict__ G2b) {
  const int z = blockIdx.z;
  const bf16_t* Ws[5] = {W0, W1, W2, W3, W4};
  bf16_t* Os[5] = {Qb, Kb, Vb, G1b, G2b};
  const float* bias = (z == 3) ? bg1 : ((z == 4) ? bg2 : nullptr);
  gemm_body(Xb, Ws[z], bias, Os[z], nullptr, (z >= 3) ? 1 : 0);
}

__global__ __launch_bounds__(256) void k_gemm_out(
    const bf16_t* __restrict__ attnB, const bf16_t* __restrict__ Wob,
    float* __restrict__ out) {
  gemm_body(attnB, Wob, nullptr, nullptr, out, 2);
}

// ---------------------------------------------------------------------------
__global__ __launch_bounds__(256) void k_cvt_all(
    const float* __restrict__ hid, const float* __restrict__ wq,
    const float* __restrict__ wk, const float* __restrict__ wv,
    const float* __restrict__ wg1, const float* __restrict__ wg2,
    const float* __restrict__ wo, bf16_t* __restrict__ Xb,
    bf16_t* __restrict__ Wd, bf16_t* __restrict__ Wcur,
    bf16_t* __restrict__ WoB) {
  const int y = blockIdx.y;
  const float* srcs[7] = {hid, wq, wk, wv, wg1, wg2, wo};
  bf16_t* dsts[7] = {Xb, Wd, Wd + WELC, Wd + 2 * WELC, Wd + 3 * WELC, Wcur,
                     WoB};
  const int n = (y == 0) ? NELC : WELC;
  const float* src = srcs[y];
  bf16_t* dst = dsts[y];
  const int idx = (blockIdx.x * 256 + threadIdx.x) * 4;
  if (idx < n) {
    const float4 f = *(const float4*)(src + idx);
    dst[idx + 0] = (bf16_t)f.x; dst[idx + 1] = (bf16_t)f.y;
    dst[idx + 2] = (bf16_t)f.z; dst[idx + 3] = (bf16_t)f.w;
  }
}

__global__ __launch_bounds__(256) void k_zero(float* __restrict__ out) {
  out[(size_t)blockIdx.x * 256 + threadIdx.x] = 0.f;
}

// ---------------------------------------------------------------------------
// k_gc: per-chunk inclusive cumsum of gate values along t (fp32 accum),
// stored fp16 IN PLACE over G; chunk totals to Btot (fp32).
// grid (NCHUNK, BB*4, 2), 64 threads. Fully coalesced b128.
// ---------------------------------------------------------------------------
__global__ __launch_bounds__(64) void k_gc(bf16_t* __restrict__ G1b,
                                           bf16_t* __restrict__ G2b,
                                           float* __restrict__ Btot) {
  const int n = blockIdx.x, b = blockIdx.y >> 2, slab = blockIdx.y & 3;
  const int e = blockIdx.z;
  short* P = (short*)(e ? G2b : G1b);
  const int d0 = slab * 512 + threadIdx.x * 8;
  const size_t base = ((size_t)(b * SEQ + n * CHUNK)) * HIDN + d0;
  float c[8] = {0.f, 0.f, 0.f, 0.f, 0.f, 0.f, 0.f, 0.f};
  for (int t = 0; t < CHUNK; t++) {
    short* p = P + base + (size_t)t * HIDN;
    const short8 g = *(const short8*)p;
    short8 o;
#pragma unroll
    for (int j = 0; j < 8; j++) { c[j] += bf2f(g[j]); o[j] = f2hf(c[j]); }
    *(short8*)p = o;
  }
  const int bh = b * 16 + (d0 >> 7);
  float* bp = Btot + ((size_t)(e * NBH + bh) * NCHUNK + n) * DD + (d0 & 127);
#pragma unroll
  for (int j = 0; j < 8; j++) bp[j] = c[j];
}

// ---------------------------------------------------------------------------
// k_sA (per e): fused U-build + intra-chunk output.
//   vT[dv][s](pad66), khatT[dk][s](pad66), k2[s][d](swz), qh[t][d](swz),
//   Ps[t][s](pad72).  U = vT x khatT -> UT global (chunk-swizzled rows).
//   P = qh x k2 (causal), o_intra = Ps x vT -> attn (w_e folded).
// ---------------------------------------------------------------------------
template <int ACC>
__global__ __launch_bounds__(256) void k_sA(
    const bf16_t* __restrict__ Qb, const bf16_t* __restrict__ Kb,
    const bf16_t* __restrict__ Vb, const bf16_t* __restrict__ Gc,
    bf16_t* __restrict__ UT, const float* __restrict__ alpha,
    bf16_t* __restrict__ attn) {
  const int n = blockIdx.x, bh = blockIdx.y;
  const int b = bh >> 4, h = bh & 15;
  const size_t rbase = ((size_t)(b * SEQ + n * CHUNK)) * HIDN + h * DD;
  const int tid = threadIdx.x;
  const int wave = tid >> 6, lane = tid & 63, qd = lane >> 4, l16 = lane & 15;
  __shared__ short vT[128 * 66];
  __shared__ short k2s[64 * 128];
  __shared__ short r3[128 * 66];  // khatT, then reused as qh (64*128 prefix)
  __shared__ short Ps[64 * 72];
  const float mx = fmaxf(alpha[0], alpha[1]);
  const float x0 = __expf(alpha[0] - mx), x1 = __expf(alpha[1] - mx);
  const float wsc = ((ACC ? x1 : x0) / (x0 + x1)) * QSCALE;

  const short* Kp = (const short*)Kb;
  const short* Vp = (const short*)Vb;
  const short* Gp = (const short*)Gc;
  const short* Qp = (const short*)Qb;

  // builds: vT (col-writes, bank d mod 32), k2 (swz b128), khatT (col-writes)
#pragma unroll
  for (int rep = 0; rep < 4; rep++) {
    const int slot = rep * 256 + tid;
    const int t = slot >> 4, ch = slot & 15;
    const size_t ga = rbase + (size_t)t * HIDN + ch * 8;
    const short8 vv = *(const short8*)(Vp + ga);
    const short8 kk = *(const short8*)(Kp + ga);
    const short8 cc = *(const short8*)(Gp + ga);
    const short8 c6 = *(const short8*)(Gp + rbase + (size_t)63 * HIDN + ch * 8);
    short8 k2v;
#pragma unroll
    for (int j = 0; j < 8; j++) {
      const int d = ch * 8 + j;
      vT[d * 66 + t] = vv[j];
      const float c = hf2f(cc[j]);
      const float kf = bf2f(kk[j]);
      k2v[j] = f2bf(kf * __expf(-c));
      r3[d * 66 + t] = f2bf(kf * __expf(hf2f(c6[j]) - c));
    }
    *(short8*)&k2s[t * 128 + ((ch ^ (t & 7)) << 3)] = k2v;
  }
  __syncthreads();

  {  // U-MFMA: C[dv][dk] = sum_s vT[dv][s] * khatT[dk][s]
    const int m0 = (wave >> 1) * 64, n0 = (wave & 1) * 64;
    const int* vTi = (const int*)vT;
    const int* r3i = (const int*)r3;
    f32x4 uacc[4][4];
#pragma unroll
    for (int i = 0; i < 4; i++)
#pragma unroll
      for (int j = 0; j < 4; j++) uacc[i][j] = (f32x4){0.f, 0.f, 0.f, 0.f};
#pragma unroll
    for (int ks = 0; ks < 2; ks++) {
      const int ch = ks * 4 + qd;
      short8 af[4], bfv[4];
#pragma unroll
      for (int i = 0; i < 4; i++) {
        const int dv = m0 + i * 16 + l16;
        const int ba = dv * 33 + ch * 4;
#pragma unroll
        for (int w2 = 0; w2 < 4; w2++) {
          const int v = vTi[ba + w2];
          af[i][2 * w2] = (short)(v & 0xffff);
          af[i][2 * w2 + 1] = (short)((unsigned)v >> 16);
        }
      }
#pragma unroll
      for (int j = 0; j < 4; j++) {
        const int dk = n0 + j * 16 + l16;
        const int ba = dk * 33 + ch * 4;
#pragma unroll
        for (int w2 = 0; w2 < 4; w2++) {
          const int v = r3i[ba + w2];
          bfv[j][2 * w2] = (short)(v & 0xffff);
          bfv[j][2 * w2 + 1] = (short)((unsigned)v >> 16);
        }
      }
#pragma unroll
      for (int i = 0; i < 4; i++)
#pragma unroll
        for (int j = 0; j < 4; j++)
          uacc[i][j] = __builtin_amdgcn_mfma_f32_16x16x32_bf16(
              af[i], bfv[j], uacc[i][j], 0, 0, 0);
    }
    short* Uo = (short*)UT + (size_t)(bh * NCHUNK + n) * (DD * DD);
#pragma unroll
    for (int i = 0; i < 4; i++)
#pragma unroll
      for (int j = 0; j < 4; j++)
#pragma unroll
        for (int r = 0; r < 4; r++) {
          const int dv = m0 + i * 16 + qd * 4 + r;
          const int dk = n0 + j * 16 + l16;
          Uo[dv * 128 + (((dk >> 3) ^ (dv & 7)) << 3) + (dk & 7)] =
              f2bf(uacc[i][j][r]);
        }
  }
  __syncthreads();

  // qh build (overwrites khatT region)
#pragma unroll
  for (int rep = 0; rep < 4; rep++) {
    const int slot = rep * 256 + tid;
    const int t = slot >> 4, ch = slot & 15;
    const size_t ga = rbase + (size_t)t * HIDN + ch * 8;
    const short8 qq = *(const short8*)(Qp + ga);
    const short8 cc = *(const short8*)(Gp + ga);
    short8 o;
#pragma unroll
    for (int j = 0; j < 8; j++)
      o[j] = f2bf(bf2f(qq[j]) * wsc * __expf(hf2f(cc[j])));
    *(short8*)&r3[t * 128 + ((ch ^ (t & 7)) << 3)] = o;
  }
  __syncthreads();

  {  // P = qh x k2 (causal): wave owns t-rows [wave*16, +16)
    f32x4 pacc[4];
#pragma unroll
    for (int j = 0; j < 4; j++) pacc[j] = (f32x4){0.f, 0.f, 0.f, 0.f};
    const int tq = wave * 16 + l16;
#pragma unroll
    for (int ks = 0; ks < 4; ks++) {
      const int ch = ks * 4 + qd;
      const short8 a = *(const short8*)&r3[tq * 128 + ((ch ^ (tq & 7)) << 3)];
#pragma unroll
      for (int j = 0; j < 4; j++) {
        const int s = j * 16 + l16;
        const short8 bq =
            *(const short8*)&k2s[s * 128 + ((ch ^ (s & 7)) << 3)];
        pacc[j] =
            __builtin_amdgcn_mfma_f32_16x16x32_bf16(a, bq, pacc[j], 0, 0, 0);
      }
    }
#pragma unroll
    for (int j = 0; j < 4; j++)
#pragma unroll
      for (int r = 0; r < 4; r++) {
        const int t = wave * 16 + qd * 4 + r, s = j * 16 + l16;
        Ps[t * 72 + s] = (t >= s) ? f2bf(pacc[j][r]) : (short)0;
      }
  }
  __syncthreads();

  // o_intra = Ps x vT
  f32x4 oacc[8];
#pragma unroll
  for (int j = 0; j < 8; j++) oacc[j] = (f32x4){0.f, 0.f, 0.f, 0.f};
  {
    const int* vTi = (const int*)vT;
    const int tq = wave * 16 + l16;
#pragma unroll
    for (int ks = 0; ks < 2; ks++) {
      const int ch = ks * 4 + qd;
      const short8 a = *(const short8*)&Ps[tq * 72 + ch * 8];
#pragma unroll
      for (int j = 0; j < 8; j++) {
        const int dv = j * 16 + l16;
        const int ba = dv * 33 + ch * 4;
        short8 bq;
#pragma unroll
        for (int w2 = 0; w2 < 4; w2++) {
          const int v = vTi[ba + w2];
          bq[2 * w2] = (short)(v & 0xffff);
          bq[2 * w2 + 1] = (short)((unsigned)v >> 16);
        }
        oacc[j] =
            __builtin_amdgcn_mfma_f32_16x16x32_bf16(a, bq, oacc[j], 0, 0, 0);
      }
    }
  }
#pragma unroll
  for (int j = 0; j < 8; j++)
#pragma unroll
    for (int r = 0; r < 4; r++) {
      const int t = wave * 16 + qd * 4 + r;
      const int dv = j * 16 + l16;
      bf16_t* p = &attn[rbase + (size_t)t * HIDN + dv];
      if (ACC) *p = (bf16_t)((float)*p + oacc[j][r]);
      else     *p = (bf16_t)oacc[j][r];
    }
}

// ---------------------------------------------------------------------------
// k_s2: sequential chunk combine (swizzled UT rows); S^T in place.
// ---------------------------------------------------------------------------
__global__ __launch_bounds__(256) void k_s2(bf16_t* __restrict__ UT,
                                            const float* __restrict__ Btot) {
  const int dg = blockIdx.x, bh = blockIdx.y;
  const int dv = dg * 8 + (threadIdx.x >> 5);
  const int dk0 = (threadIdx.x & 31) * 4;
  const int pos = dv * 128 + (((dk0 >> 3) ^ (dv & 7)) << 3) + (dk0 & 7);
  float st[4] = {0.f, 0.f, 0.f, 0.f};
  for (int nn = 0; nn < NCHUNK; nn++) {
    short* p = (short*)UT + (size_t)(bh * NCHUNK + nn) * (DD * DD) + pos;
    const float4 bp =
        *(const float4*)(Btot + (size_t)(bh * NCHUNK + nn) * DD + dk0);
    short u0 = p[0], u1 = p[1], u2 = p[2], u3 = p[3];
    p[0] = f2bf(st[0]); p[1] = f2bf(st[1]);
    p[2] = f2bf(st[2]); p[3] = f2bf(st[3]);
    st[0] = st[0] * __expf(bp.x) + bf2f(u0);
    st[1] = st[1] * __expf(bp.y) + bf2f(u1);
    st[2] = st[2] * __expf(bp.z) + bf2f(u2);
    st[3] = st[3] * __expf(bp.w) + bf2f(u3);
  }
}

// ---------------------------------------------------------------------------
// k_s3b: inter-chunk  attn += qh @ S.  S staged via gload16 (async, overlaps
// qh rebuild); both read as swizzled b128 frags.
// ---------------------------------------------------------------------------
__global__ __launch_bounds__(256) void k_s3b(
    const bf16_t* __restrict__ Qb, const bf16_t* __restrict__ Gc,
    const bf16_t* __restrict__ UT, const float* __restrict__ alpha,
    const int e, bf16_t* __restrict__ attn) {
  const int n = blockIdx.x, bh = blockIdx.y;
  const int b = bh >> 4, h = bh & 15;
  const size_t rbase = ((size_t)(b * SEQ + n * CHUNK)) * HIDN + h * DD;
  const int tid = threadIdx.x;
  const int wave = tid >> 6, lane = tid & 63, qd = lane >> 4, l16 = lane & 15;
  __shared__ short qh[64 * 128];
  __shared__ short Ss[128 * 128];
  const float mx = fmaxf(alpha[0], alpha[1]);
  const float x0 = __expf(alpha[0] - mx), x1 = __expf(alpha[1] - mx);
  const float wsc = ((e ? x1 : x0) / (x0 + x1)) * QSCALE;

  // async-stage S tile (2048 x 16B chunks, lane-linear, layout preserved)
  const short* Sp = (const short*)UT + (size_t)(bh * NCHUNK + n) * (DD * DD);
#pragma unroll
  for (int rep = 0; rep < 8; rep++) {
    const int c = rep * 256 + tid;
    gload_lds16(Sp + c * 8, &Ss[c * 8]);
  }
  // qh rebuild (overlaps the async loads)
  const short* Qp = (const short*)Qb;
  const short* Gp = (const short*)Gc;
#pragma unroll
  for (int rep = 0; rep < 4; rep++) {
    const int slot = rep * 256 + tid;
    const int t = slot >> 4, ch = slot & 15;
    const size_t ga = rbase + (size_t)t * HIDN + ch * 8;
    const short8 qq = *(const short8*)(Qp + ga);
    const short8 cc = *(const short8*)(Gp + ga);
    short8 o;
#pragma unroll
    for (int j = 0; j < 8; j++)
      o[j] = f2bf(bf2f(qq[j]) * wsc * __expf(hf2f(cc[j])));
    *(short8*)&qh[t * 128 + ((ch ^ (t & 7)) << 3)] = o;
  }
  __syncthreads();

  f32x4 oacc[8];
#pragma unroll
  for (int j = 0; j < 8; j++) oacc[j] = (f32x4){0.f, 0.f, 0.f, 0.f};
  const int tq = wave * 16 + l16;
#pragma unroll
  for (int ks = 0; ks < 4; ks++) {
    const int ch = ks * 4 + qd;
    const short8 a = *(const short8*)&qh[tq * 128 + ((ch ^ (tq & 7)) << 3)];
#pragma unroll
    for (int j = 0; j < 8; j++) {
      const int dv = j * 16 + l16;
      const short8 bq = *(const short8*)&Ss[dv * 128 + ((ch ^ (dv & 7)) << 3)];
      oacc[j] =
          __builtin_amdgcn_mfma_f32_16x16x32_bf16(a, bq, oacc[j], 0, 0, 0);
    }
  }
#pragma unroll
  for (int j = 0; j < 8; j++)
#pragma unroll
    for (int r = 0; r < 4; r++) {
      const int t = wave * 16 + qd * 4 + r;
      const int dv = j * 16 + l16;
      bf16_t* p = &attn[rbase + (size_t)t * HIDN + dv];
      *p = (bf16_t)((float)*p + oacc[j][r]);
    }
}

// ---------------------------------------------------------------------------
extern "C" void kernel_launch(void* const* d_in, const int* in_sizes, int n_in,
                              void* d_out, int out_size, void* d_ws,
                              size_t ws_size, hipStream_t stream) {
  const float* hid  = (const float*)d_in[0];
  const float* wq   = (const float*)d_in[1];
  const float* wk   = (const float*)d_in[2];
  const float* wv   = (const float*)d_in[3];
  const float* wo   = (const float*)d_in[4];
  const float* wg1  = (const float*)d_in[5];
  const float* bg1  = (const float*)d_in[6];
  const float* wg2  = (const float*)d_in[7];
  const float* bg2  = (const float*)d_in[8];
  const float* alph = (const float*)d_in[9];
  float* out = (float*)d_out;
  (void)in_sizes; (void)n_in; (void)out_size;

  char* ws = (char*)d_ws;
  size_t off = 0;
  auto alloc = [&](size_t bytes) -> void* {
    void* p = ws + off;
    off += (bytes + 255) & ~(size_t)255;
    return p;
  };
  const size_t NEL = NELC, WEL = WELC;
  bf16_t* Xb   = (bf16_t*)alloc(NEL * 2);  // X; reused as attn
  bf16_t* Wcur = (bf16_t*)alloc(WEL * 2);  // Wg2
  bf16_t* WoB  = (bf16_t*)alloc(WEL * 2);  // Wo
  bf16_t* Qb   = (bf16_t*)alloc(NEL * 2);
  bf16_t* Kb   = (bf16_t*)alloc(NEL * 2);
  bf16_t* Vb   = (bf16_t*)alloc(NEL * 2);
  bf16_t* G1b  = (bf16_t*)alloc(NEL * 2);
  bf16_t* G2b  = (bf16_t*)alloc(NEL * 2);
  float*  Btot = (float*) alloc((size_t)2 * NBH * NCHUNK * DD * 4);
  bf16_t* Wd = (bf16_t*)d_out;  // weights, then U/S states, then final out
  bf16_t* UT = (bf16_t*)d_out;

  if (off > ws_size) {  // diagnostic fallback
    k_zero<<<dim3((unsigned)(NEL / 256)), 256, 0, stream>>>(out);
    return;
  }

  k_cvt_all<<<dim3(8192, 7), 256, 0, stream>>>(hid, wq, wk, wv, wg1, wg2, wo,
                                               Xb, Wd, Wcur, WoB);
  k_gemm_proj<<<dim3(32, 16, 5), 256, 0, stream>>>(
      Xb, Wd, Wd + WEL, Wd + 2 * WEL, Wd + 3 * WEL, Wcur, bg1, bg2, Qb, Kb, Vb,
      G1b, G2b);
  k_gc<<<dim3(NCHUNK, BB * 4, 2), 64, 0, stream>>>(G1b, G2b, Btot);

  const dim3 gs(NCHUNK, NBH), g2(16, NBH);
  const size_t BSTRIDE = (size_t)NBH * NCHUNK * DD;
  // e = 0
  k_sA<0><<<gs, 256, 0, stream>>>(Qb, Kb, Vb, G1b, UT, alph, Xb);
  k_s2<<<g2, 256, 0, stream>>>(UT, Btot);
  k_s3b<<<gs, 256, 0, stream>>>(Qb, G1b, UT, alph, 0, Xb);
  // e = 1
  k_sA<1><<<gs, 256, 0, stream>>>(Qb, Kb, Vb, G2b, UT, alph, Xb);
  k_s2<<<g2, 256, 0, stream>>>(UT, Btot + BSTRIDE);
  k_s3b<<<gs, 256, 0, stream>>>(Qb, G2b, UT, alph, 1, Xb);

  k_gemm_out<<<dim3(32, 16), 256, 0, stream>>>(Xb, WoB, out);
}